// Round 1
// baseline (595.457 us; speedup 1.0000x reference)
//
#include <hip/hip_runtime.h>

// CropConv: 3x3 conv, 64->64 ch, B=16, H=W=128, stride 1, pad 1, then zero
// rows/cols [44,84) x [44,84).
//
// Round 1: direct fp32 conv. Block(256) computes (b, oc-pair, 8 rows x 128 cols).
// Per input channel: stage 10x128 input rows in LDS, uniform (scalar) weight
// loads, 72 FMA / 18 LDS-reads per thread per ic.

#define B_ 16
#define C_ 64
#define H_ 128
#define W_ 128

__global__ __launch_bounds__(256) void cropconv_kernel(
    const float* __restrict__ x, const float* __restrict__ wgt,
    float* __restrict__ out)
{
    // grid: (ocpair=32, htile=16, b=16); ocpair fastest => 32 blocks sharing
    // one input tile are dispatch-adjacent (L2 locality across XCDs).
    const int ocpair = blockIdx.x;   // 0..31
    const int ht     = blockIdx.y;   // 0..15
    const int b      = blockIdx.z;   // 0..15
    const int oc0 = ocpair * 2;
    const int h0  = ht * 8;          // output rows h0..h0+7

    const int t  = threadIdx.x;      // 0..255
    const int w  = t & 127;
    const int hq = t >> 7;           // 0..1
    const int hl = hq * 4;           // local output row base (0 or 4)

    __shared__ float lds[10][128];   // rows h0-1 .. h0+8 of current ic

    float acc[2][4];
    #pragma unroll
    for (int i = 0; i < 2; ++i)
        #pragma unroll
        for (int j = 0; j < 4; ++j) acc[i][j] = 0.f;

    const float* xb = x + (size_t)b * C_ * H_ * W_;
    const float* wp0 = wgt + (size_t)oc0 * C_ * 9;       // [ic*9 + kh*3 + kw]
    const float* wp1 = wp0 + (size_t)C_ * 9;

    for (int ic = 0; ic < C_; ++ic) {
        const float* xc = xb + (size_t)ic * H_ * W_;
        __syncthreads();
        // stage 10 rows x 128 cols (zero-pad out-of-range rows)
        #pragma unroll
        for (int k = 0; k < 5; ++k) {
            int idx = t + k * 256;          // 0..1279
            int r   = idx >> 7;             // 0..9
            int c   = idx & 127;
            int gr  = h0 - 1 + r;
            float v = (gr >= 0 && gr < H_) ? xc[gr * W_ + c] : 0.f;
            lds[r][c] = v;
        }
        __syncthreads();

        // block-uniform weights -> scalar loads
        float wa[9], wb[9];
        #pragma unroll
        for (int q = 0; q < 9; ++q) {
            wa[q] = wp0[ic * 9 + q];
            wb[q] = wp1[ic * 9 + q];
        }

        // 6 rows x 3 cols input window for this thread's 4 output rows
        float in[6][3];
        #pragma unroll
        for (int r = 0; r < 6; ++r) {
            int rr = hl + r;                 // lds row; covers outputs hl..hl+3
            float left  = (w > 0)   ? lds[rr][w - 1] : 0.f;
            float mid   =             lds[rr][w];
            float right = (w < 127) ? lds[rr][w + 1] : 0.f;
            in[r][0] = left; in[r][1] = mid; in[r][2] = right;
        }

        #pragma unroll
        for (int j = 0; j < 4; ++j) {
            #pragma unroll
            for (int dh = 0; dh < 3; ++dh) {
                #pragma unroll
                for (int dw = 0; dw < 3; ++dw) {
                    float v = in[j + dh][dw];
                    acc[0][j] = fmaf(v, wa[dh * 3 + dw], acc[0][j]);
                    acc[1][j] = fmaf(v, wb[dh * 3 + dw], acc[1][j]);
                }
            }
        }
    }

    // store with crop mask: zero iff h in [44,84) AND w in [44,84)
    const bool win_w = (w >= 44 && w < 84);
    #pragma unroll
    for (int i = 0; i < 2; ++i) {
        float* ob = out + (((size_t)b * C_ + (oc0 + i)) * H_ + h0) * (size_t)W_;
        #pragma unroll
        for (int j = 0; j < 4; ++j) {
            int hloc = hl + j;
            int h = h0 + hloc;
            bool zero = win_w && (h >= 44 && h < 84);
            ob[hloc * W_ + w] = zero ? 0.f : acc[i][j];
        }
    }
}

extern "C" void kernel_launch(void* const* d_in, const int* in_sizes, int n_in,
                              void* d_out, int out_size, void* d_ws, size_t ws_size,
                              hipStream_t stream) {
    const float* x   = (const float*)d_in[0];   // [16,64,128,128] fp32
    const float* wgt = (const float*)d_in[1];   // [64,64,3,3] fp32
    float* out       = (float*)d_out;           // [16,64,128,128] fp32

    dim3 grid(32, 16, 16);   // (ocpair, htile, batch)
    dim3 block(256);
    cropconv_kernel<<<grid, block, 0, stream>>>(x, wgt, out);
}

// Round 2
// 191.117 us; speedup vs baseline: 3.1157x; 3.1157x over previous
//
#include <hip/hip_runtime.h>
#include <stdint.h>

// CropConv via implicit GEMM + MFMA (bf16 in, fp32 accum).
//   M=64 (oc), K=576 (ic*3*3), N=262144 (b*h*w)
// Pre-pass 1: weights -> bf16 [kk=9][oc=64][ic=64]    (73,728 B in ws)
// Pre-pass 2: input   -> bf16 NHWC padded [16][130][130][64], zero halo
// Main: no-LDS register GEMM, block = 64oc x (2h x 128w), wave = 4x4 MFMA tiles.

#define B_ 16
#define C_ 64
#define H_ 128
#define W_ 128
#define HP 130
#define WP 130

typedef float f32x4 __attribute__((ext_vector_type(4)));
typedef short bf16x8 __attribute__((ext_vector_type(8)));

__device__ inline unsigned short f2bf(float f) {
    union { float f; uint32_t u; } v; v.f = f;
    uint32_t u = v.u + 0x7FFF + ((v.u >> 16) & 1);   // RNE
    return (unsigned short)(u >> 16);
}

// ---- pre-pass: weights [oc][ic][3][3] fp32 -> [kk][oc][ic] bf16 ----
__global__ __launch_bounds__(256) void xform_weight(
    const float* __restrict__ wgt, uint16_t* __restrict__ Wb)
{
    int idx = blockIdx.x * 256 + threadIdx.x;     // < 36864
    int kk  = idx >> 12;                          // 0..8
    int rem = idx & 4095;
    int oc  = rem >> 6, ic = rem & 63;
    Wb[idx] = f2bf(wgt[((size_t)oc * 64 + ic) * 9 + kk]);
}

// ---- pre-pass: zero the pad halo of X' (ws is poisoned each call) ----
__global__ __launch_bounds__(256) void zero_halo(uint32_t* __restrict__ Xu)
{
    int idx = blockIdx.x * 256 + threadIdx.x;     // per-b halo uints: 16512
    int b   = blockIdx.y;
    if (idx >= 16512) return;
    if (idx < 8320) {                             // rows 0 and 129, full 130 w
        int r = (idx < 4160) ? 0 : 129;
        int j = idx % 4160;                       // w'*32 + u
        Xu[((size_t)b * HP + r) * WP * 32 + j] = 0;
    } else {                                      // cols 0 and 129, rows 1..128
        int j = idx - 8320;
        int c = (j < 4096) ? 0 : 129;
        int k = j & 4095;
        int row = 1 + (k >> 5);
        Xu[(((size_t)b * HP + row) * WP + c) * 32 + (k & 31)] = 0;
    }
}

// ---- pre-pass: x [b][ic][h][w] fp32 -> X' [b][h+1][w+1][ic] bf16 ----
__global__ __launch_bounds__(256) void xform_input(
    const float* __restrict__ x, uint32_t* __restrict__ Xu)
{
    const int t = threadIdx.x;
    const int h = blockIdx.x;
    const int b = blockIdx.y;
    const int w  = t >> 1;
    const int ih = (t & 1) * 32;                  // ic half
    const float* xp = x + (((size_t)(b * C_ + ih)) * H_ + h) * W_ + w;
    uint32_t u[16];
    #pragma unroll
    for (int j = 0; j < 16; ++j) {
        float v0 = xp[(size_t)(2 * j)     * (H_ * W_)];
        float v1 = xp[(size_t)(2 * j + 1) * (H_ * W_)];
        u[j] = (uint32_t)f2bf(v0) | ((uint32_t)f2bf(v1) << 16);
    }
    uint32_t* dst = Xu + (((size_t)(b * HP + h + 1)) * WP + w + 1) * 32 + (t & 1) * 16;
    uint4* d4 = (uint4*)dst;
    const uint4* s4 = (const uint4*)u;
    #pragma unroll
    for (int k = 0; k < 4; ++k) d4[k] = s4[k];
}

// ---- main: register-only implicit GEMM ----
// grid (64 htiles, 16 b), block 256 = 4 waves.
// wave wv: output rows h = 2*htile + (wv>>1), w-range = (wv&1)*64 .. +64
// per wave: 4 m-tiles (16 oc) x 4 n-tiles (16 w), K-loop = 9 (kh,kw) x 2 ic-chunks.
__global__ __launch_bounds__(256) void conv_mfma(
    const uint4* __restrict__ Wq,   // [9][64][8] uint4  (8 bf16 each)
    const uint4* __restrict__ Xq,   // [16][130][130][8] uint4
    float* __restrict__ out)
{
    const int t    = threadIdx.x;
    const int lane = t & 63;
    const int wv   = t >> 6;
    const int n    = lane & 15;     // n for B-frag, m for A-frag
    const int q    = lane >> 4;
    const int b    = blockIdx.y;
    const int h    = blockIdx.x * 2 + (wv >> 1);
    const int wb   = (wv & 1) * 64;

    f32x4 acc[4][4];
    #pragma unroll
    for (int i = 0; i < 4; ++i)
        #pragma unroll
        for (int tt = 0; tt < 4; ++tt)
            acc[i][tt] = (f32x4){0.f, 0.f, 0.f, 0.f};

    // uint4-granular bases
    const int aB = n * 8 + q;                                  // +kk*512 +i*128 +ch*4
    const int xB = ((b * HP + h) * WP + wb + n) * 8 + q;       // row h+kh = (h_in+1)

    #pragma unroll
    for (int kh = 0; kh < 3; ++kh) {
        #pragma unroll
        for (int kw = 0; kw < 3; ++kw) {
            const int kk = kh * 3 + kw;
            #pragma unroll
            for (int ch = 0; ch < 2; ++ch) {
                bf16x8 a[4], bb[4];
                #pragma unroll
                for (int i = 0; i < 4; ++i)
                    a[i] = __builtin_bit_cast(bf16x8,
                        Wq[aB + kk * 512 + i * 128 + ch * 4]);
                #pragma unroll
                for (int tt = 0; tt < 4; ++tt)
                    bb[tt] = __builtin_bit_cast(bf16x8,
                        Xq[xB + (kh * WP + kw) * 8 + tt * 128 + ch * 4]);
                #pragma unroll
                for (int i = 0; i < 4; ++i)
                    #pragma unroll
                    for (int tt = 0; tt < 4; ++tt)
                        acc[i][tt] = __builtin_amdgcn_mfma_f32_16x16x32_bf16(
                            a[i], bb[tt], acc[i][tt], 0, 0, 0);
            }
        }
    }

    // epilogue: C row = oc = i*16 + q*4 + r, col = w = wb + tt*16 + n
    const bool hz = (h >= 44 && h < 84);
    #pragma unroll
    for (int i = 0; i < 4; ++i) {
        #pragma unroll
        for (int tt = 0; tt < 4; ++tt) {
            const int w0 = wb + tt * 16 + n;
            const bool zz = hz && (w0 >= 44 && w0 < 84);
            #pragma unroll
            for (int r = 0; r < 4; ++r) {
                const int oc = i * 16 + q * 4 + r;
                out[(((size_t)b * C_ + oc) * H_ + h) * W_ + w0] =
                    zz ? 0.f : acc[i][tt][r];
            }
        }
    }
}

// ---- fallback (round-1 direct conv) if ws too small ----
__global__ __launch_bounds__(256) void cropconv_direct(
    const float* __restrict__ x, const float* __restrict__ wgt,
    float* __restrict__ out)
{
    const int ocpair = blockIdx.x, ht = blockIdx.y, b = blockIdx.z;
    const int oc0 = ocpair * 2, h0 = ht * 8;
    const int t = threadIdx.x, w = t & 127, hl = (t >> 7) * 4;
    __shared__ float lds[10][128];
    float acc[2][4];
    #pragma unroll
    for (int i = 0; i < 2; ++i)
        #pragma unroll
        for (int j = 0; j < 4; ++j) acc[i][j] = 0.f;
    const float* xb  = x + (size_t)b * C_ * H_ * W_;
    const float* wp0 = wgt + (size_t)oc0 * C_ * 9;
    const float* wp1 = wp0 + (size_t)C_ * 9;
    for (int ic = 0; ic < C_; ++ic) {
        const float* xc = xb + (size_t)ic * H_ * W_;
        __syncthreads();
        #pragma unroll
        for (int k = 0; k < 5; ++k) {
            int idx = t + k * 256, r = idx >> 7, c = idx & 127, gr = h0 - 1 + r;
            lds[r][c] = (gr >= 0 && gr < H_) ? xc[gr * W_ + c] : 0.f;
        }
        __syncthreads();
        float wa[9], wbv[9];
        #pragma unroll
        for (int qq = 0; qq < 9; ++qq) { wa[qq] = wp0[ic*9+qq]; wbv[qq] = wp1[ic*9+qq]; }
        float in[6][3];
        #pragma unroll
        for (int r = 0; r < 6; ++r) {
            int rr = hl + r;
            in[r][0] = (w > 0)   ? lds[rr][w-1] : 0.f;
            in[r][1] =             lds[rr][w];
            in[r][2] = (w < 127) ? lds[rr][w+1] : 0.f;
        }
        #pragma unroll
        for (int j = 0; j < 4; ++j)
            #pragma unroll
            for (int dh = 0; dh < 3; ++dh)
                #pragma unroll
                for (int dw = 0; dw < 3; ++dw) {
                    float v = in[j+dh][dw];
                    acc[0][j] = fmaf(v, wa[dh*3+dw], acc[0][j]);
                    acc[1][j] = fmaf(v, wbv[dh*3+dw], acc[1][j]);
                }
    }
    const bool win_w = (w >= 44 && w < 84);
    #pragma unroll
    for (int i = 0; i < 2; ++i) {
        float* ob = out + (((size_t)b * C_ + (oc0+i)) * H_ + h0) * (size_t)W_;
        #pragma unroll
        for (int j = 0; j < 4; ++j) {
            int h = h0 + hl + j;
            ob[(hl+j) * W_ + w] = (win_w && h >= 44 && h < 84) ? 0.f : acc[i][j];
        }
    }
}

extern "C" void kernel_launch(void* const* d_in, const int* in_sizes, int n_in,
                              void* d_out, int out_size, void* d_ws, size_t ws_size,
                              hipStream_t stream) {
    const float* x   = (const float*)d_in[0];
    const float* wgt = (const float*)d_in[1];
    float* out       = (float*)d_out;

    const size_t W_BYTES = 9 * 64 * 64 * 2;                        // 73,728
    const size_t X_BYTES = (size_t)B_ * HP * WP * 64 * 2;          // 34,611,200
    if (ws_size >= W_BYTES + X_BYTES) {
        uint16_t* Wb = (uint16_t*)d_ws;
        uint32_t* Xu = (uint32_t*)((char*)d_ws + W_BYTES);
        xform_weight<<<dim3(144), dim3(256), 0, stream>>>(wgt, Wb);
        zero_halo<<<dim3(65, 16), dim3(256), 0, stream>>>(Xu);
        xform_input<<<dim3(128, 16), dim3(256), 0, stream>>>(x, Xu);
        conv_mfma<<<dim3(64, 16), dim3(256), 0, stream>>>(
            (const uint4*)Wb, (const uint4*)Xu, out);
    } else {
        cropconv_direct<<<dim3(32, 16, 16), dim3(256), 0, stream>>>(x, wgt, out);
    }
}

// Round 3
// 170.865 us; speedup vs baseline: 3.4850x; 1.1185x over previous
//
#include <hip/hip_runtime.h>
#include <stdint.h>

// CropConv via implicit GEMM + MFMA (bf16 in, fp32 accum).
//   M=64 (oc), K=576 (ic*3*3), N=262144 (b*h*w)
// Pre-pass 1: weights -> bf16 [kk=9][oc=64][ic=64]
// Pre-pass 2 (fused): input -> bf16 NHWC padded [16][130][130][64] + halo zeros
// Main: block = 64oc x 2h x 128w. Input tile (4 rows x 128 cols x 64ic bf16 =
// 64 KiB) staged ONCE in LDS via global_load_lds(16B), XOR-swizzled to kill
// bank conflicts; 18 straight-line K-steps (no barriers in K-loop); A (weights)
// from global (L1-hot, 72 KiB shared device-wide).

#define B_ 16
#define C_ 64
#define H_ 128
#define W_ 128
#define HP 130
#define WP 130

typedef float f32x4 __attribute__((ext_vector_type(4)));
typedef short bf16x8 __attribute__((ext_vector_type(8)));

__device__ inline unsigned short f2bf(float f) {
    union { float f; uint32_t u; } v; v.f = f;
    uint32_t u = v.u + 0x7FFF + ((v.u >> 16) & 1);   // RNE
    return (unsigned short)(u >> 16);
}

// ---- pre-pass: weights [oc][ic][3][3] fp32 -> [kk][oc][ic] bf16 ----
__global__ __launch_bounds__(256) void xform_weight(
    const float* __restrict__ wgt, uint16_t* __restrict__ Wb)
{
    int idx = blockIdx.x * 256 + threadIdx.x;     // < 36864
    int kk  = idx >> 12;
    int rem = idx & 4095;
    int oc  = rem >> 6, ic = rem & 63;
    Wb[idx] = f2bf(wgt[((size_t)oc * 64 + ic) * 9 + kk]);
}

// ---- fused pre-pass: x [b][ic][h][w] fp32 -> X' [b][h'][w'][ic] bf16,
//      halo rows/cols zeroed. grid (130, 16), block 256. ----
__global__ __launch_bounds__(256) void xform_input_fused(
    const float* __restrict__ x, uint32_t* __restrict__ Xu)
{
    const int t  = threadIdx.x;
    const int hp = blockIdx.x;                    // padded row 0..129
    const int b  = blockIdx.y;
    uint4* rowbase = (uint4*)(Xu + ((size_t)(b * HP + hp)) * WP * 32);

    if (hp == 0 || hp == HP - 1) {                // halo row: zero 1040 uint4
        uint4 z; z.x = z.y = z.z = z.w = 0;
        for (int k = t; k < WP * 8; k += 256) rowbase[k] = z;
        return;
    }
    if (t < 16) {                                 // halo cols 0 and 129
        uint4 z; z.x = z.y = z.z = z.w = 0;
        int c = (t < 8) ? 0 : (WP - 1);
        rowbase[c * 8 + (t & 7)] = z;
    }
    const int h  = hp - 1;
    const int w  = t >> 1;
    const int ih = (t & 1) * 32;                  // ic half
    const float* xp = x + (((size_t)(b * C_ + ih)) * H_ + h) * W_ + w;
    uint32_t u[16];
    #pragma unroll
    for (int j = 0; j < 16; ++j) {
        float v0 = xp[(size_t)(2 * j)     * (H_ * W_)];
        float v1 = xp[(size_t)(2 * j + 1) * (H_ * W_)];
        u[j] = (uint32_t)f2bf(v0) | ((uint32_t)f2bf(v1) << 16);
    }
    uint4* d4 = rowbase + ((w + 1) * 8 + (t & 1) * 4);
    const uint4* s4 = (const uint4*)u;
    #pragma unroll
    for (int k = 0; k < 4; ++k) d4[k] = s4[k];
}

// ---- main: LDS-staged implicit GEMM ----
// grid (64 htiles, 16 b), block 256 = 4 waves; wave = (h = 2*ht + (wv>>1),
// w-range (wv&1)*64..+64), 4 m-tiles x 4 n-tiles of 16x16x32 MFMA.
// LDS: [r:4][c:128][j':8] uint4, j' = (j + c) & 7  (XOR-rotate swizzle).
__global__ __launch_bounds__(256, 2) void conv_mfma(
    const uint4* __restrict__ Wq,   // [9][64][8] uint4
    const uint4* __restrict__ Xq,   // [16][130][130][8] uint4
    float* __restrict__ out)
{
    __shared__ uint4 lds[4096];     // 64 KiB

    const int t    = threadIdx.x;
    const int lane = t & 63;
    const int wv   = t >> 6;
    const int n    = lane & 15;
    const int q    = lane >> 4;
    const int b    = blockIdx.y;
    const int h0   = blockIdx.x * 2;
    const int h    = h0 + (wv >> 1);
    const int wb   = (wv & 1) * 64;

    // ---- stage input rows h0-1..h0+2 (= Xq rows h0..h0+3), cols 1..128 ----
    {
        const uint4* src = Xq + (size_t)(b * HP + h0) * WP * 8;
        #pragma unroll
        for (int k = 0; k < 16; ++k) {
            int i  = k * 256 + t;            // LDS uint4 index
            int r  = i >> 10;                // 0..3
            int c  = (i >> 3) & 127;         // 0..127
            int jp = i & 7;                  // swizzled slot
            int j  = (jp - c) & 7;           // original uint4-in-col
            const uint4* g = src + (size_t)(r * WP + (c + 1)) * 8 + j;
            __builtin_amdgcn_global_load_lds(
                (const __attribute__((address_space(1))) uint32_t*)g,
                (__attribute__((address_space(3))) uint32_t*)&lds[k * 256 + wv * 64],
                16, 0, 0);
        }
    }
    __syncthreads();   // drains vmcnt before barrier

    f32x4 acc[4][4];
    #pragma unroll
    for (int i = 0; i < 4; ++i)
        #pragma unroll
        for (int tt = 0; tt < 4; ++tt)
            acc[i][tt] = (f32x4){0.f, 0.f, 0.f, 0.f};

    const int aB = n * 8 + q;                 // Wq uint4 base
    const bool lz = (wb + n) == 0;            // col -1 lane (kw=0, tt=0)
    const bool rz = (wb + n) == 79;           // col 128 lane (kw=2, tt=3)
    const bf16x8 zfrag = 0;

    #pragma unroll
    for (int kh = 0; kh < 3; ++kh) {
        const int row = (wv >> 1) + kh;       // LDS row 0..3
        #pragma unroll
        for (int kw = 0; kw < 3; ++kw) {
            const int kk = kh * 3 + kw;
            #pragma unroll
            for (int ch = 0; ch < 2; ++ch) {
                bf16x8 a[4], bb[4];
                #pragma unroll
                for (int i = 0; i < 4; ++i)
                    a[i] = __builtin_bit_cast(bf16x8,
                        Wq[aB + kk * 512 + i * 128 + ch * 4]);
                #pragma unroll
                for (int tt = 0; tt < 4; ++tt) {
                    int c  = wb + tt * 16 + n + kw - 1;     // -1..128
                    int cc = min(max(c, 0), 127);
                    int idx = (row * 128 + cc) * 8 + ((ch * 4 + q + cc) & 7);
                    bf16x8 v = __builtin_bit_cast(bf16x8, lds[idx]);
                    if (kw == 0 && tt == 0) v = lz ? zfrag : v;
                    if (kw == 2 && tt == 3) v = rz ? zfrag : v;
                    bb[tt] = v;
                }
                #pragma unroll
                for (int i = 0; i < 4; ++i)
                    #pragma unroll
                    for (int tt = 0; tt < 4; ++tt)
                        acc[i][tt] = __builtin_amdgcn_mfma_f32_16x16x32_bf16(
                            a[i], bb[tt], acc[i][tt], 0, 0, 0);
            }
        }
    }

    // epilogue: oc = i*16 + q*4 + r, w = wb + tt*16 + n
    const bool hz = (h >= 44 && h < 84);
    #pragma unroll
    for (int i = 0; i < 4; ++i) {
        #pragma unroll
        for (int tt = 0; tt < 4; ++tt) {
            const int w0 = wb + tt * 16 + n;
            const bool zz = hz && (w0 >= 44 && w0 < 84);
            #pragma unroll
            for (int r = 0; r < 4; ++r) {
                const int oc = i * 16 + q * 4 + r;
                out[(((size_t)b * C_ + oc) * H_ + h) * W_ + w0] =
                    zz ? 0.f : acc[i][tt][r];
            }
        }
    }
}

// ---- fallback (round-1 direct conv) if ws too small ----
__global__ __launch_bounds__(256) void cropconv_direct(
    const float* __restrict__ x, const float* __restrict__ wgt,
    float* __restrict__ out)
{
    const int ocpair = blockIdx.x, ht = blockIdx.y, b = blockIdx.z;
    const int oc0 = ocpair * 2, h0 = ht * 8;
    const int t = threadIdx.x, w = t & 127, hl = (t >> 7) * 4;
    __shared__ float sm[10][128];
    float acc[2][4];
    #pragma unroll
    for (int i = 0; i < 2; ++i)
        #pragma unroll
        for (int j = 0; j < 4; ++j) acc[i][j] = 0.f;
    const float* xb  = x + (size_t)b * C_ * H_ * W_;
    const float* wp0 = wgt + (size_t)oc0 * C_ * 9;
    const float* wp1 = wp0 + (size_t)C_ * 9;
    for (int ic = 0; ic < C_; ++ic) {
        const float* xc = xb + (size_t)ic * H_ * W_;
        __syncthreads();
        #pragma unroll
        for (int k = 0; k < 5; ++k) {
            int idx = t + k * 256, r = idx >> 7, c = idx & 127, gr = h0 - 1 + r;
            sm[r][c] = (gr >= 0 && gr < H_) ? xc[gr * W_ + c] : 0.f;
        }
        __syncthreads();
        float wa[9], wbv[9];
        #pragma unroll
        for (int qq = 0; qq < 9; ++qq) { wa[qq] = wp0[ic*9+qq]; wbv[qq] = wp1[ic*9+qq]; }
        float in[6][3];
        #pragma unroll
        for (int r = 0; r < 6; ++r) {
            int rr = hl + r;
            in[r][0] = (w > 0)   ? sm[rr][w-1] : 0.f;
            in[r][1] =             sm[rr][w];
            in[r][2] = (w < 127) ? sm[rr][w+1] : 0.f;
        }
        #pragma unroll
        for (int j = 0; j < 4; ++j)
            #pragma unroll
            for (int dh = 0; dh < 3; ++dh)
                #pragma unroll
                for (int dw = 0; dw < 3; ++dw) {
                    float v = in[j+dh][dw];
                    acc[0][j] = fmaf(v, wa[dh*3+dw], acc[0][j]);
                    acc[1][j] = fmaf(v, wbv[dh*3+dw], acc[1][j]);
                }
    }
    const bool win_w = (w >= 44 && w < 84);
    #pragma unroll
    for (int i = 0; i < 2; ++i) {
        float* ob = out + (((size_t)b * C_ + (oc0+i)) * H_ + h0) * (size_t)W_;
        #pragma unroll
        for (int j = 0; j < 4; ++j) {
            int h = h0 + hl + j;
            ob[(hl+j) * W_ + w] = (win_w && h >= 44 && h < 84) ? 0.f : acc[i][j];
        }
    }
}

extern "C" void kernel_launch(void* const* d_in, const int* in_sizes, int n_in,
                              void* d_out, int out_size, void* d_ws, size_t ws_size,
                              hipStream_t stream) {
    const float* x   = (const float*)d_in[0];
    const float* wgt = (const float*)d_in[1];
    float* out       = (float*)d_out;

    const size_t W_BYTES = 9 * 64 * 64 * 2;                        // 73,728
    const size_t X_BYTES = (size_t)B_ * HP * WP * 64 * 2;          // 34,611,200
    if (ws_size >= W_BYTES + X_BYTES) {
        uint16_t* Wb = (uint16_t*)d_ws;
        uint32_t* Xu = (uint32_t*)((char*)d_ws + W_BYTES);
        xform_weight<<<dim3(144), dim3(256), 0, stream>>>(wgt, Wb);
        xform_input_fused<<<dim3(130, 16), dim3(256), 0, stream>>>(x, Xu);
        conv_mfma<<<dim3(64, 16), dim3(256), 0, stream>>>(
            (const uint4*)Wb, (const uint4*)Xu, out);
    } else {
        cropconv_direct<<<dim3(32, 16, 16), dim3(256), 0, stream>>>(x, wgt, out);
    }
}